// Round 1
// baseline (836.369 us; speedup 1.0000x reference)
//
#include <hip/hip_runtime.h>

#define B_SZ   16384
#define F_N    26
#define V_N    100000
#define D_N    64
#define H1_N   512
#define H2_N   256
#define IN_DIM 1989
#define KPAD   2048

typedef _Float16 half8_t __attribute__((ext_vector_type(8)));
typedef _Float16 half4_t __attribute__((ext_vector_type(4)));
typedef float    floatx4 __attribute__((ext_vector_type(4)));

#define MFMA16(a, b, c) __builtin_amdgcn_mfma_f32_16x16x32_f16((a), (b), (c), 0, 0, 0)

__device__ __forceinline__ void load_lds16(const void* g, void* l) {
    __builtin_amdgcn_global_load_lds(
        (const __attribute__((address_space(1))) unsigned int*)g,
        (__attribute__((address_space(3))) unsigned int*)l,
        16, 0, 0);
}

// ---------------------------------------------------------------------------
// Weight prep: WT[n][k] = fp16(W[k][n]), zero pad k in [K, Kpad)
// ---------------------------------------------------------------------------
__global__ __launch_bounds__(256) void prep_w(const float* __restrict__ W,
                                              _Float16* __restrict__ WT,
                                              int K, int N, int Kpad) {
    int t = blockIdx.x * 256 + threadIdx.x;
    if (t >= N * Kpad) return;
    int n = t / Kpad;
    int k = t - n * Kpad;
    WT[t] = (k < K) ? (_Float16)W[(size_t)k * N + n] : (_Float16)0.f;
}

// ---------------------------------------------------------------------------
// Gather + interactions. 4 samples per block (one per wave).
// joint row: [0,1664) = emb flat (fp16), [1664,1989) = upper-tri gram, pad->0
// ---------------------------------------------------------------------------
#define EMB_STRIDE 72                      // 64 + 8 pad halfs (breaks bank alias)
#define EMB_PER_SAMPLE (32 * EMB_STRIDE)   // 32 rows (26 data + 6 zero)

__global__ __launch_bounds__(256) void gather_interact(
        const int* __restrict__ idx,
        const float* __restrict__ tables,
        _Float16* __restrict__ joint) {
    __shared__ __align__(16) _Float16 embh[4 * EMB_PER_SAMPLE];
    __shared__ int sidx[4 * F_N];
    const int tid = threadIdx.x;
    const int b0  = blockIdx.x * 4;

    if (tid < 4 * F_N) sidx[tid] = idx[(size_t)b0 * F_N + tid];

    // zero MFMA pad rows 26..31 (k in [0,64))
    for (int z = tid; z < 4 * 6 * 16; z += 256) {
        int s = z / 96, rem = z % 96;
        int f = F_N + rem / 16, d4 = (rem % 16) * 4;
        half4_t zz; zz[0] = 0; zz[1] = 0; zz[2] = 0; zz[3] = 0;
        *(half4_t*)(embh + s * EMB_PER_SAMPLE + f * EMB_STRIDE + d4) = zz;
    }
    __syncthreads();

    // gather: 4 samples x 26 rows x 16 float4 chunks
    for (int c = tid; c < 4 * F_N * 16; c += 256) {
        int s = c / 416, rem = c % 416;
        int f = rem >> 4, d4 = (rem & 15) * 4;
        const float4 v = *(const float4*)(tables +
                           ((size_t)f * V_N + sidx[s * F_N + f]) * D_N + d4);
        half4_t h;
        h[0] = (_Float16)v.x; h[1] = (_Float16)v.y;
        h[2] = (_Float16)v.z; h[3] = (_Float16)v.w;
        *(half4_t*)(embh + s * EMB_PER_SAMPLE + f * EMB_STRIDE + d4) = h;
        *(half4_t*)(joint + (size_t)(b0 + s) * KPAD + f * D_N + d4) = h;
    }
    // zero joint K-pad
    for (int q = tid; q < 4 * (KPAD - IN_DIM); q += 256) {
        int s = q / (KPAD - IN_DIM), p = q % (KPAD - IN_DIM);
        joint[(size_t)(b0 + s) * KPAD + IN_DIM + p] = (_Float16)0.f;
    }
    __syncthreads();

    // per-wave gram via MFMA: gram = E (32x64) x E^T (64x32), E^T B-frag == E A-frag
    const int wave = tid >> 6, lane = tid & 63;
    const _Float16* eb = embh + wave * EMB_PER_SAMPLE;
    const int fr = lane & 15;
    const int fk = (lane >> 4) * 8;
    floatx4 a00 = {0.f, 0.f, 0.f, 0.f};
    floatx4 a01 = {0.f, 0.f, 0.f, 0.f};
    floatx4 a11 = {0.f, 0.f, 0.f, 0.f};
    #pragma unroll
    for (int k0 = 0; k0 < 64; k0 += 32) {
        half8_t f0 = *(const half8_t*)(eb + fr * EMB_STRIDE + k0 + fk);
        half8_t f1 = *(const half8_t*)(eb + (16 + fr) * EMB_STRIDE + k0 + fk);
        a00 = MFMA16(f0, f0, a00);   // m in [0,16),  n in [0,16)
        a01 = MFMA16(f0, f1, a01);   // m in [0,16),  n in [16,32)
        a11 = MFMA16(f1, f1, a11);   // m in [16,32), n in [16,32)
        // (1,0) tile skipped: m>n always
    }
    // extract upper triangle: D[row=(lane>>4)*4+r][col=lane&15]
    _Float16* jrow = joint + (size_t)(b0 + wave) * KPAD + F_N * D_N;
    #pragma unroll
    for (int r = 0; r < 4; ++r) {
        int mb = (lane >> 4) * 4 + r;
        {   // tile (0,0): m=mb, n=fr
            int m = mb, n = fr;
            if (m < n) jrow[(m * (51 - m)) / 2 + n - m - 1] = (_Float16)a00[r];
        }
        {   // tile (0,1): m=mb, n=16+fr
            int m = mb, n = 16 + fr;
            if (n < F_N) jrow[(m * (51 - m)) / 2 + n - m - 1] = (_Float16)a01[r];
        }
        {   // tile (1,1): m=16+mb, n=16+fr
            int m = 16 + mb, n = 16 + fr;
            if (m < n && n < F_N) jrow[(m * (51 - m)) / 2 + n - m - 1] = (_Float16)a11[r];
        }
    }
}

// ---------------------------------------------------------------------------
// C = relu(A @ Bt^T + bias), fp16 in/out, fp32 accumulate.
// A: M x K row-major (lda), Bt: N x K row-major (ldb), C: M x N (ldc) fp16
// 128x128 tile, BK=32, 256 threads (4 waves, each 64x64), m97 structure.
// ---------------------------------------------------------------------------
__global__ __launch_bounds__(256) void gemm_bt(
        const _Float16* __restrict__ A, int lda,
        const _Float16* __restrict__ Bt, int ldb,
        const float* __restrict__ bias,
        _Float16* __restrict__ C, int ldc,
        int K, int nblocks) {
    __shared__ __align__(16) _Float16 As[128 * 32];
    __shared__ __align__(16) _Float16 Bs[128 * 32];
    const int tid  = threadIdx.x;
    const int wave = tid >> 6;
    const int lane = tid & 63;
    const int bm = blockIdx.x / nblocks;
    const int bn = blockIdx.x % nblocks;
    const int m0 = bm * 128, n0 = bn * 128;

    // staging: 512 chunks of 16B per tile; chunk c -> row c>>2, k-part (c&3)*8
    const int c0 = tid, c1 = tid + 256;
    const _Float16* ag0 = A  + (size_t)(m0 + (c0 >> 2)) * lda + (c0 & 3) * 8;
    const _Float16* ag1 = A  + (size_t)(m0 + (c1 >> 2)) * lda + (c1 & 3) * 8;
    const _Float16* bg0 = Bt + (size_t)(n0 + (c0 >> 2)) * ldb + (c0 & 3) * 8;
    const _Float16* bg1 = Bt + (size_t)(n0 + (c1 >> 2)) * ldb + (c1 & 3) * 8;
    char* asd0 = (char*)As + wave * 1024;
    char* asd1 = (char*)As + 4096 + wave * 1024;
    char* bsd0 = (char*)Bs + wave * 1024;
    char* bsd1 = (char*)Bs + 4096 + wave * 1024;

    floatx4 acc[4][4];
    #pragma unroll
    for (int i = 0; i < 4; ++i)
        #pragma unroll
        for (int j = 0; j < 4; ++j) acc[i][j] = (floatx4){0.f, 0.f, 0.f, 0.f};

    const int wm = (wave >> 1) * 64;
    const int wn = (wave & 1) * 64;
    const int fr = lane & 15;
    const int fk = (lane >> 4) * 8;

    for (int k0 = 0; k0 < K; k0 += 32) {
        load_lds16(ag0 + k0, asd0);
        load_lds16(ag1 + k0, asd1);
        load_lds16(bg0 + k0, bsd0);
        load_lds16(bg1 + k0, bsd1);
        __syncthreads();
        half8_t af[4], bf[4];
        #pragma unroll
        for (int i = 0; i < 4; ++i)
            af[i] = *(const half8_t*)(As + (wm + i * 16 + fr) * 32 + fk);
        #pragma unroll
        for (int j = 0; j < 4; ++j)
            bf[j] = *(const half8_t*)(Bs + (wn + j * 16 + fr) * 32 + fk);
        #pragma unroll
        for (int i = 0; i < 4; ++i)
            #pragma unroll
            for (int j = 0; j < 4; ++j)
                acc[i][j] = MFMA16(af[i], bf[j], acc[i][j]);
        __syncthreads();
    }

    const int colb = n0 + wn + fr;
    const int rowb = m0 + wm + (lane >> 4) * 4;
    #pragma unroll
    for (int j = 0; j < 4; ++j) {
        const int c = colb + j * 16;
        const float bv = bias[c];
        #pragma unroll
        for (int i = 0; i < 4; ++i)
            #pragma unroll
            for (int r = 0; r < 4; ++r) {
                float v = acc[i][j][r] + bv;
                v = fmaxf(v, 0.f);
                C[(size_t)(rowb + i * 16 + r) * ldc + c] = (_Float16)v;
            }
    }
}

// ---------------------------------------------------------------------------
// out[row] = h2[row,:] . W3 + b3   (one wave per row)
// ---------------------------------------------------------------------------
__global__ __launch_bounds__(256) void final_gemv(
        const _Float16* __restrict__ h2, const float* __restrict__ W3,
        const float* __restrict__ b3, float* __restrict__ out) {
    const int lane = threadIdx.x & 63;
    const int row  = blockIdx.x * 4 + (threadIdx.x >> 6);
    const float4 w = *(const float4*)(W3 + lane * 4);
    const half4_t h = *(const half4_t*)(h2 + (size_t)row * H2_N + lane * 4);
    float s = (float)h[0] * w.x + (float)h[1] * w.y +
              (float)h[2] * w.z + (float)h[3] * w.w;
    #pragma unroll
    for (int off = 32; off > 0; off >>= 1) s += __shfl_down(s, off, 64);
    if (lane == 0) out[row] = s + b3[0];
}

// ---------------------------------------------------------------------------
extern "C" void kernel_launch(void* const* d_in, const int* in_sizes, int n_in,
                              void* d_out, int out_size, void* d_ws, size_t ws_size,
                              hipStream_t stream) {
    const int*   idx    = (const int*)d_in[0];
    const float* tables = (const float*)d_in[1];
    const float* W1     = (const float*)d_in[2];
    const float* b1     = (const float*)d_in[3];
    const float* W2     = (const float*)d_in[4];
    const float* b2     = (const float*)d_in[5];
    const float* W3     = (const float*)d_in[6];
    const float* b3     = (const float*)d_in[7];
    float* out = (float*)d_out;

    char* ws = (char*)d_ws;
    // joint: 16384*2048*2      =  67,108,864
    // W1T:   512*2048*2        =   2,097,152
    // h1:    16384*512*2       =  16,777,216
    // W2T:   256*512*2         =     262,144
    // h2:    16384*256*2       =   8,388,608   total ~94.6 MB
    _Float16* joint = (_Float16*)(ws);
    _Float16* W1T   = (_Float16*)(ws + 67108864);
    _Float16* h1    = (_Float16*)(ws + 69206016);
    _Float16* W2T   = (_Float16*)(ws + 85983232);
    _Float16* h2    = (_Float16*)(ws + 86245376);

    prep_w<<<(H1_N * KPAD + 255) / 256, 256, 0, stream>>>(W1, W1T, IN_DIM, H1_N, KPAD);
    prep_w<<<(H2_N * H1_N + 255) / 256, 256, 0, stream>>>(W2, W2T, H1_N, H2_N, H1_N);
    gather_interact<<<B_SZ / 4, 256, 0, stream>>>(idx, tables, joint);
    gemm_bt<<<(B_SZ / 128) * (H1_N / 128), 256, 0, stream>>>(
        joint, KPAD, W1T, KPAD, b1, h1, H1_N, KPAD, H1_N / 128);
    gemm_bt<<<(B_SZ / 128) * (H2_N / 128), 256, 0, stream>>>(
        h1, H1_N, W2T, H1_N, b2, h2, H2_N, H1_N, H2_N / 128);
    final_gemv<<<B_SZ / 4, 256, 0, stream>>>(h2, W3, b3, out);
}